// Round 7
// baseline (300.576 us; speedup 1.0000x reference)
//
#include <hip/hip_runtime.h>
#include <stdint.h>
#include <math.h>

// ---------------------------------------------------------------------------
// Sampler: temperature-scale -> top-k threshold -> Gumbel-max categorical.
// Exact reproduction of the JAX reference (threefry partitionable, key 42).
//
// R6 structure: ONE fused kernel (B*SEG blocks x 256 thr) + 1KB memset.
//   All blocks: stream segment (8-deep float4 loads), LDS-compact x >= SPEC_F,
//   copy to private global slot, __threadfence, atomicAdd(done[r]).
//   The block observing old==SEG-1 (last for its row) finalizes the row:
//   gather <=2048 candidates, exact kth via 3-level histogram with
//   wave-parallel select, exact division filter, gumbel + shfl argmax.
//   Finalize overlaps other rows' collects; zero extra launches.
//   Fallback (speculation failure): full-histogram re-read, 256 thr.
// ---------------------------------------------------------------------------

#define CBLOCK 256
#define SEG 16
#define LCAP 128        // per-segment candidate slot (E[c]~50 for N(0,1))
#define NBIN  4096
#define TOTC  (SEG * LCAP)   // 2048
#define SLACK 64u
#define SPEC_F 2.5f
#define SPEC_KEY 0xC0200000u   // f2key(2.5f)

__device__ __forceinline__ uint32_t rotl32(uint32_t x, uint32_t r) {
  return (x << r) | (x >> (32u - r));
}

__device__ __forceinline__ uint32_t f2key(float x) {
  uint32_t b = __float_as_uint(x);
  return (b & 0x80000000u) ? ~b : (b | 0x80000000u);
}
__device__ __forceinline__ float key2f(uint32_t k) {
  uint32_t b = (k & 0x80000000u) ? (k & 0x7FFFFFFFu) : ~k;
  return __uint_as_float(b);
}

// Threefry-2x32, key = (0, 42)
__device__ __forceinline__ void tf2x32(uint32_t x0, uint32_t x1,
                                       uint32_t &o0, uint32_t &o1) {
  const uint32_t k0 = 0u, k1 = 42u;
  const uint32_t k2 = k0 ^ k1 ^ 0x1BD11BDAu;
  x0 += k0; x1 += k1;
#define TF_R(r) { x0 += x1; x1 = rotl32(x1, (r)); x1 ^= x0; }
  TF_R(13u) TF_R(15u) TF_R(26u) TF_R(6u)
  x0 += k1; x1 += k2 + 1u;
  TF_R(17u) TF_R(29u) TF_R(16u) TF_R(24u)
  x0 += k2; x1 += k0 + 2u;
  TF_R(13u) TF_R(15u) TF_R(26u) TF_R(6u)
  x0 += k0; x1 += k1 + 3u;
  TF_R(17u) TF_R(29u) TF_R(16u) TF_R(24u)
  x0 += k1; x1 += k2 + 4u;
  TF_R(13u) TF_R(15u) TF_R(26u) TF_R(6u)
  x0 += k2; x1 += k0 + 5u;
#undef TF_R
  o0 = x0; o1 = x1;
}

__device__ __forceinline__ float gumbel_at(uint32_t j) {
  uint32_t o0, o1;
  tf2x32(0u, j, o0, o1);
  uint32_t bits = o0 ^ o1;
  float f = __uint_as_float((bits >> 9) | 0x3F800000u) - 1.0f;
  const float TINY = 1.17549435e-38f;
  float u = (f == 0.0f) ? TINY : f;
  return -logf(-logf(u));
}

// ---- wave-parallel descending-rank select over 64 bins -------------------
// tid<64 participate. Thread t supplies v = count of bin (63-t). Returns
// (wave-uniform) the bin holding the Kt-th largest and 1-based in-bin rank.
__device__ __forceinline__ void wave_sel64(uint32_t v, uint32_t Kt,
                                           uint32_t &sel, uint32_t &rank) {
  const int lane = threadIdx.x & 63;
  uint32_t P = v;
#pragma unroll
  for (int d = 1; d < 64; d <<= 1) {
    uint32_t n = __shfl_up(P, d, 64);
    if (lane >= d) P += n;
  }
  unsigned long long m = __ballot(P >= Kt);
  int t0 = (int)__ffsll(m) - 1;
  uint32_t Pt = __shfl(P, t0, 64);
  uint32_t vt = __shfl(v, t0, 64);
  sel = (uint32_t)(63 - t0);
  rank = Kt - (Pt - vt);
}

// ---- serial select over hist[4096] (fallback paths only) ------------------
__device__ void find4096(uint32_t* hist, uint32_t* super, uint32_t Kt,
                         uint32_t* s_bin, uint32_t* s_rank) {
  const int tid = threadIdx.x;
  if (tid < 64) {
    uint32_t s = 0;
    for (int i = 0; i < 64; ++i) s += hist[tid * 64 + i];
    super[tid] = s;
  }
  __syncthreads();
  if (tid == 0) {
    uint32_t acc = 0; int sb = 0;
    for (int s = 63; s >= 0; --s) {
      if (acc + super[s] >= Kt) { sb = s; break; }
      acc += super[s];
    }
    uint32_t bfound = (uint32_t)(sb * 64);
    for (int i = 63; i >= 0; --i) {
      uint32_t bin = (uint32_t)(sb * 64 + i);
      if (acc + hist[bin] >= Kt) { bfound = bin; break; }
      acc += hist[bin];
    }
    *s_bin = bfound; *s_rank = Kt - acc;
  }
  __syncthreads();
}

// gumbel-argmax over kept candidates; shfl wave-reduce + serial wave combine
__device__ void gumbel_argmax_cand(const uint32_t* cand_key, const int* cand_idx,
                                   uint32_t cnt, float kth_scaled, float temp,
                                   uint32_t jbase, uint32_t* scratch,
                                   int* out, int r) {
  const int tid = threadIdx.x;
  const int lane = tid & 63;
  const int wid = tid >> 6;
  float bv = -INFINITY;
  int bi = 0x7FFFFFFF;
  for (int i = tid; i < (int)cnt; i += blockDim.x) {
    float sc = key2f(cand_key[i]) / temp;
    if (sc >= kth_scaled) {
      int v = cand_idx[i];
      float g = gumbel_at(jbase + (uint32_t)v);
      float val = sc + g;
      if (val > bv || (val == bv && v < bi)) { bv = val; bi = v; }
    }
  }
#pragma unroll
  for (int d = 32; d > 0; d >>= 1) {
    float ov = __shfl_down(bv, d, 64);
    int oi = __shfl_down(bi, d, 64);
    if (ov > bv || (ov == bv && oi < bi)) { bv = ov; bi = oi; }
  }
  __syncthreads();
  float* rv = (float*)scratch;
  int*   ri = (int*)(scratch + 64);
  if (lane == 0) { rv[wid] = bv; ri[wid] = bi; }
  __syncthreads();
  if (tid == 0) {
    int nw = (int)(blockDim.x >> 6);
    float fv = rv[0]; int fi = ri[0];
    for (int w = 1; w < nw; ++w) {
      float ov = rv[w]; int oi = ri[w];
      if (ov > fv || (ov == fv && oi < fi)) { fv = ov; fi = oi; }
    }
    out[r] = fi;
  }
}

// ======================= fused kernel ======================================
__global__ __launch_bounds__(CBLOCK)
void fused_kernel(const float* __restrict__ logits,
                  const float* __restrict__ temps,
                  const int* __restrict__ topk_p,
                  int* __restrict__ out, int V,
                  uint32_t* __restrict__ seg_cnts,
                  uint2* __restrict__ entries,
                  uint32_t* __restrict__ done) {
  const int r   = blockIdx.x / SEG;
  const int seg = blockIdx.x % SEG;
  const int tid = threadIdx.x;
  const float* row = logits + (size_t)r * (size_t)V;
  const float4* row4 = (const float4*)row;
  const int n4 = V >> 2;
  const int chunk = (n4 + SEG - 1) / SEG;
  const int s4 = seg * chunk;
  const int e4 = min(n4, s4 + chunk);

  // LDS pool: collect aliases the front; finalize uses all of it.
  //   hist      = pool[0 .. 4095]
  //   cand_key  = pool[4096 .. 4096+2047]
  //   cand_idx  = pool[6144 .. 6144+2047]
  __shared__ uint32_t pool[NBIN + 2 * TOTC];
  __shared__ uint32_t super[64];
  __shared__ uint32_t scnt[SEG];
  __shared__ uint32_t soff[SEG + 1];
  __shared__ uint32_t l_cnt, s_flag, s_bin, s_rank, s_kth, s_cnt;
  __shared__ float    s_kth_scaled;

  uint32_t* l_key = pool;            // [LCAP]
  uint32_t* l_idx = pool + LCAP;     // [LCAP]

  if (tid == 0) l_cnt = 0u;
  __syncthreads();

  // ---- collect phase: 8-deep conditional float4 loads ----
  for (int i = s4 + tid; i < e4; i += 8 * CBLOCK) {
    float4 x[8];
#pragma unroll
    for (int k = 0; k < 8; ++k) {
      int idx = i + k * CBLOCK;
      x[k] = (idx < e4) ? row4[idx] : make_float4(0.f, 0.f, 0.f, 0.f);
    }
#pragma unroll
    for (int k = 0; k < 8; ++k) {
      int idx = i + k * CBLOCK;
      if (x[k].x >= SPEC_F) { uint32_t p = atomicAdd(&l_cnt, 1u);
        if (p < LCAP) { l_key[p] = f2key(x[k].x); l_idx[p] = ((uint32_t)idx << 2) + 0; } }
      if (x[k].y >= SPEC_F) { uint32_t p = atomicAdd(&l_cnt, 1u);
        if (p < LCAP) { l_key[p] = f2key(x[k].y); l_idx[p] = ((uint32_t)idx << 2) + 1; } }
      if (x[k].z >= SPEC_F) { uint32_t p = atomicAdd(&l_cnt, 1u);
        if (p < LCAP) { l_key[p] = f2key(x[k].z); l_idx[p] = ((uint32_t)idx << 2) + 2; } }
      if (x[k].w >= SPEC_F) { uint32_t p = atomicAdd(&l_cnt, 1u);
        if (p < LCAP) { l_key[p] = f2key(x[k].w); l_idx[p] = ((uint32_t)idx << 2) + 3; } }
    }
  }
  if (seg == SEG - 1) {
    for (int j = (n4 << 2) + tid; j < V; j += CBLOCK) {
      float x = row[j];
      if (x >= SPEC_F) {
        uint32_t p = atomicAdd(&l_cnt, 1u);
        if (p < LCAP) { l_key[p] = f2key(x); l_idx[p] = (uint32_t)j; }
      }
    }
  }
  __syncthreads();
  const uint32_t c = l_cnt;
  uint2* dst = entries + ((size_t)r * SEG + (size_t)seg) * LCAP;
  const uint32_t w = (c < LCAP) ? c : LCAP;
  for (uint32_t k = tid; k < w; k += CBLOCK)
    dst[k] = make_uint2(l_key[k], l_idx[k]);
  if (tid == 0) seg_cnts[r * SEG + seg] = c;   // true count (may exceed LCAP)
  __syncthreads();

  // ---- last-block-done handoff ----
  if (tid == 0) {
    __threadfence();
    uint32_t old = atomicAdd(&done[r], 1u);
    s_flag = (old == SEG - 1) ? 1u : 0u;
  }
  __syncthreads();
  if (!s_flag) return;
  __threadfence();   // acquire: make other blocks' entries/seg_cnts visible

  // ================= finalize phase (this block only) ======================
  const uint32_t K = (uint32_t)(*topk_p);
  const float temp = temps[r];
  const uint32_t jbase = (uint32_t)r * (uint32_t)V;
  uint32_t* hist = pool;
  uint32_t* cand_key = pool + NBIN;
  int*      cand_idx = (int*)(pool + NBIN + TOTC);

  if (tid < SEG) scnt[tid] = seg_cnts[r * SEG + tid];
  __syncthreads();
  if (tid == 0) {
    uint32_t acc = 0; uint32_t ok = 1;
    for (int s = 0; s < SEG; ++s) {
      soff[s] = acc;
      uint32_t cc = scnt[s];
      if (cc > LCAP) ok = 0;
      acc += (cc < LCAP) ? cc : LCAP;
    }
    soff[SEG] = acc;
    s_flag = ok;
  }
  __syncthreads();
  const uint32_t cnt = soff[SEG];

  if (s_flag && cnt >= K) {
    // ---- parallel gather over the fixed SEG x LCAP grid ----
    const uint2* base = entries + (size_t)r * TOTC;
    for (int idx = tid; idx < TOTC; idx += CBLOCK) {
      int s = idx >> 7;              // / LCAP
      int k = idx & (LCAP - 1);
      if ((uint32_t)k < scnt[s]) {
        uint2 e = base[idx];
        uint32_t p = soff[s] + (uint32_t)k;
        cand_key[p] = e.x; cand_idx[p] = (int)e.y;
      }
    }
    __syncthreads();

    // ---- exact kth: 3-level histogram, wave-parallel select ----
    for (int i = tid; i < NBIN; i += CBLOCK) hist[i] = 0u;
    __syncthreads();
    for (int i = tid; i < (int)cnt; i += CBLOCK)
      atomicAdd(&hist[cand_key[i] >> 20], 1u);
    __syncthreads();
    if (tid < 64) {
      uint32_t s = 0;
      for (int i = 0; i < 64; ++i) s += hist[tid * 64 + i];
      super[tid] = s;
    }
    __syncthreads();
    if (tid < 64) {
      uint32_t sb, rs;
      wave_sel64(super[63 - tid], K, sb, rs);
      uint32_t s2, r2;
      wave_sel64(hist[sb * 64 + (63 - tid)], rs, s2, r2);
      if (tid == 0) { s_bin = sb * 64 + s2; s_rank = r2; }
    }
    __syncthreads();
    const uint32_t binA = s_bin;
    const uint32_t rA = s_rank;

    for (int i = tid; i < NBIN; i += CBLOCK) hist[i] = 0u;
    __syncthreads();
    for (int i = tid; i < (int)cnt; i += CBLOCK) {
      uint32_t key = cand_key[i];
      if ((key >> 20) == binA) atomicAdd(&hist[(key >> 8) & 0xFFFu], 1u);
    }
    __syncthreads();
    if (tid < 64) {
      uint32_t s = 0;
      for (int i = 0; i < 64; ++i) s += hist[tid * 64 + i];
      super[tid] = s;
    }
    __syncthreads();
    if (tid < 64) {
      uint32_t sb, rs;
      wave_sel64(super[63 - tid], rA, sb, rs);
      uint32_t s2, r2;
      wave_sel64(hist[sb * 64 + (63 - tid)], rs, s2, r2);
      if (tid == 0) { s_bin = sb * 64 + s2; s_rank = r2; }
    }
    __syncthreads();
    const uint32_t binB = s_bin;
    const uint32_t rB = s_rank;

    for (int i = tid; i < 256; i += CBLOCK) hist[i] = 0u;
    __syncthreads();
    for (int i = tid; i < (int)cnt; i += CBLOCK) {
      uint32_t key = cand_key[i];
      if ((key >> 8) == ((binA << 12) | binB)) atomicAdd(&hist[key & 0xFFu], 1u);
    }
    __syncthreads();
    if (tid < 64) {
      uint32_t mi = 63 - tid;
      uint32_t v = hist[mi * 4] + hist[mi * 4 + 1] + hist[mi * 4 + 2] + hist[mi * 4 + 3];
      uint32_t mm, rm;
      wave_sel64(v, rB, mm, rm);
      if (tid == 0) {
        uint32_t acc = 0; uint32_t b3 = mm * 4;
        for (int j = 3; j >= 0; --j) {
          uint32_t cc = hist[mm * 4 + j];
          if (acc + cc >= rm) { b3 = mm * 4 + (uint32_t)j; break; }
          acc += cc;
        }
        uint32_t kth = (binA << 20) | (binB << 8) | b3;
        s_kth = kth;
        s_kth_scaled = key2f(kth) / temp;
      }
    }
    __syncthreads();
    if (s_kth >= SPEC_KEY + SLACK) {
      gumbel_argmax_cand(cand_key, cand_idx, cnt, s_kth_scaled, temp,
                         jbase, hist, out, r);
      return;
    }
    __syncthreads();
  }

  // ---------------- fallback: full histogram over the row (L3-warm) -------
  for (int i = tid; i < NBIN; i += CBLOCK) hist[i] = 0u;
  if (tid == 0) s_cnt = 0u;
  __syncthreads();
  for (int i = tid; i < n4; i += CBLOCK) {
    float4 x = row4[i];
    atomicAdd(&hist[f2key(x.x) >> 20], 1u);
    atomicAdd(&hist[f2key(x.y) >> 20], 1u);
    atomicAdd(&hist[f2key(x.z) >> 20], 1u);
    atomicAdd(&hist[f2key(x.w) >> 20], 1u);
  }
  for (int i = (n4 << 2) + tid; i < V; i += CBLOCK)
    atomicAdd(&hist[f2key(row[i]) >> 20], 1u);
  __syncthreads();
  find4096(hist, super, K, &s_bin, &s_rank);
  const uint32_t b1 = s_bin;
  const uint32_t r1 = s_rank;

  // collect everything >= binfloor - slack into cand (capacity TOTC)
  uint32_t lo = b1 << 20;
  lo = (lo >= SLACK) ? (lo - SLACK) : 0u;
  if (tid == 0) s_cnt = 0u;
  __syncthreads();
  for (int i = tid; i < V; i += CBLOCK) {
    uint32_t key = f2key(row[i]);
    if (key >= lo) {
      uint32_t p = atomicAdd(&s_cnt, 1u);
      if (p < TOTC) { cand_key[p] = key; cand_idx[p] = i; }
    }
  }
  __syncthreads();
  const uint32_t cnt2 = s_cnt;

  if (cnt2 <= TOTC) {
    // exact kth among cand via serial 3-level refinement
    for (int i = tid; i < NBIN; i += CBLOCK) hist[i] = 0u;
    __syncthreads();
    for (int i = tid; i < (int)cnt2; i += CBLOCK)
      atomicAdd(&hist[cand_key[i] >> 20], 1u);
    __syncthreads();
    find4096(hist, super, K, &s_bin, &s_rank);
    const uint32_t bA = s_bin; const uint32_t rA2 = s_rank;
    for (int i = tid; i < NBIN; i += CBLOCK) hist[i] = 0u;
    __syncthreads();
    for (int i = tid; i < (int)cnt2; i += CBLOCK) {
      uint32_t key = cand_key[i];
      if ((key >> 20) == bA) atomicAdd(&hist[(key >> 8) & 0xFFFu], 1u);
    }
    __syncthreads();
    find4096(hist, super, rA2, &s_bin, &s_rank);
    const uint32_t bB = s_bin; const uint32_t rB2 = s_rank;
    for (int i = tid; i < 256; i += CBLOCK) hist[i] = 0u;
    __syncthreads();
    for (int i = tid; i < (int)cnt2; i += CBLOCK) {
      uint32_t key = cand_key[i];
      if ((key >> 8) == ((bA << 12) | bB)) atomicAdd(&hist[key & 0xFFu], 1u);
    }
    __syncthreads();
    if (tid == 0) {
      uint32_t acc = 0; uint32_t b3 = 0;
      for (int i = 255; i >= 0; --i) {
        if (acc + hist[i] >= rB2) { b3 = (uint32_t)i; break; }
        acc += hist[i];
      }
      uint32_t kth = (bA << 20) | (bB << 8) | b3;
      s_kth = kth;
      s_kth_scaled = key2f(kth) / temp;
    }
    __syncthreads();
    gumbel_argmax_cand(cand_key, cand_idx, cnt2, s_kth_scaled, temp,
                       jbase, hist, out, r);
    return;
  }

  // pathological duplicate-heavy rows: refine + argmax from global memory
  for (int i = tid; i < NBIN; i += CBLOCK) hist[i] = 0u;
  __syncthreads();
  for (int i = tid; i < V; i += CBLOCK) {
    uint32_t key = f2key(row[i]);
    if ((key >> 20) == b1) atomicAdd(&hist[(key >> 8) & 0xFFFu], 1u);
  }
  __syncthreads();
  find4096(hist, super, r1, &s_bin, &s_rank);
  const uint32_t b2 = s_bin; const uint32_t r2 = s_rank;
  for (int i = tid; i < 256; i += CBLOCK) hist[i] = 0u;
  __syncthreads();
  for (int i = tid; i < V; i += CBLOCK) {
    uint32_t key = f2key(row[i]);
    if ((key >> 8) == ((b1 << 12) | b2)) atomicAdd(&hist[key & 0xFFu], 1u);
  }
  __syncthreads();
  if (tid == 0) {
    uint32_t acc = 0; uint32_t b3 = 0;
    for (int i = 255; i >= 0; --i) {
      if (acc + hist[i] >= r2) { b3 = (uint32_t)i; break; }
      acc += hist[i];
    }
    uint32_t kth = (b1 << 20) | (b2 << 8) | b3;
    s_kth = kth;
    s_kth_scaled = key2f(kth) / temp;
  }
  __syncthreads();
  const float kth_scaled = s_kth_scaled;

  float bv = -INFINITY;
  int bi = 0x7FFFFFFF;
  for (int i = tid; i < V; i += CBLOCK) {
    float x = row[i];
    float sc = x / temp;
    if (sc >= kth_scaled) {
      float g = gumbel_at(jbase + (uint32_t)i);
      float val = sc + g;
      if (val > bv || (val == bv && i < bi)) { bv = val; bi = i; }
    }
  }
#pragma unroll
  for (int d = 32; d > 0; d >>= 1) {
    float ov = __shfl_down(bv, d, 64);
    int oi = __shfl_down(bi, d, 64);
    if (ov > bv || (ov == bv && oi < bi)) { bv = ov; bi = oi; }
  }
  __syncthreads();
  {
    float* rv = (float*)hist;
    int*   ri = (int*)(hist + 64);
    int lane = tid & 63, wid = tid >> 6;
    if (lane == 0) { rv[wid] = bv; ri[wid] = bi; }
    __syncthreads();
    if (tid == 0) {
      int nw = CBLOCK >> 6;
      float fv = rv[0]; int fi = ri[0];
      for (int w2 = 1; w2 < nw; ++w2) {
        float ov = rv[w2]; int oi = ri[w2];
        if (ov > fv || (ov == fv && oi < fi)) { fv = ov; fi = oi; }
      }
      out[r] = fi;
    }
  }
}

// ============== monolithic kernel (used only if ws too small) ==============
__global__ __launch_bounds__(1024)
void sampler_mono(const float* __restrict__ logits,
                  const float* __restrict__ temps,
                  const int* __restrict__ topk_p,
                  int* __restrict__ out, int B, int V) {
  const int r = blockIdx.x;
  const int tid = threadIdx.x;
  const uint32_t K = (uint32_t)(*topk_p);
  const float temp = temps[r];
  const float* row = logits + (size_t)r * (size_t)V;
  const uint32_t jbase = (uint32_t)r * (uint32_t)V;

  __shared__ uint32_t hist[NBIN];
  __shared__ uint32_t super[64];
  __shared__ uint32_t cand_key[TOTC];
  __shared__ int      cand_idx[TOTC];
  __shared__ uint32_t s_cnt, s_bin, s_rank, s_kth;
  __shared__ float    s_kth_scaled;

  const int n4 = V >> 2;
  const float4* row4 = (const float4*)row;

  if (tid == 0) s_cnt = 0u;
  __syncthreads();
  for (int i = tid; i < n4; i += 1024) {
    float4 x = row4[i];
    float s[4] = {x.x, x.y, x.z, x.w};
#pragma unroll
    for (int q = 0; q < 4; ++q) {
      if (s[q] >= SPEC_F) {
        uint32_t p = atomicAdd(&s_cnt, 1u);
        if (p < TOTC) { cand_key[p] = f2key(s[q]); cand_idx[p] = (i << 2) + q; }
      }
    }
  }
  for (int i = (n4 << 2) + tid; i < V; i += 1024) {
    float x = row[i];
    if (x >= SPEC_F) {
      uint32_t p = atomicAdd(&s_cnt, 1u);
      if (p < TOTC) { cand_key[p] = f2key(x); cand_idx[p] = i; }
    }
  }
  __syncthreads();
  uint32_t cnt = s_cnt;
  bool spec_ok = false;
  if (cnt >= K && cnt <= TOTC) {
    for (int i = tid; i < NBIN; i += 1024) hist[i] = 0u;
    __syncthreads();
    for (int i = tid; i < (int)cnt; i += 1024)
      atomicAdd(&hist[cand_key[i] >> 20], 1u);
    __syncthreads();
    find4096(hist, super, K, &s_bin, &s_rank);
    const uint32_t bA = s_bin; const uint32_t rA = s_rank;
    for (int i = tid; i < NBIN; i += 1024) hist[i] = 0u;
    __syncthreads();
    for (int i = tid; i < (int)cnt; i += 1024) {
      uint32_t key = cand_key[i];
      if ((key >> 20) == bA) atomicAdd(&hist[(key >> 8) & 0xFFFu], 1u);
    }
    __syncthreads();
    find4096(hist, super, rA, &s_bin, &s_rank);
    const uint32_t bB = s_bin; const uint32_t rB = s_rank;
    for (int i = tid; i < 256; i += 1024) hist[i] = 0u;
    __syncthreads();
    for (int i = tid; i < (int)cnt; i += 1024) {
      uint32_t key = cand_key[i];
      if ((key >> 8) == ((bA << 12) | bB)) atomicAdd(&hist[key & 0xFFu], 1u);
    }
    __syncthreads();
    if (tid == 0) {
      uint32_t acc = 0; uint32_t b3 = 0;
      for (int i = 255; i >= 0; --i) {
        if (acc + hist[i] >= rB) { b3 = (uint32_t)i; break; }
        acc += hist[i];
      }
      uint32_t kth = (bA << 20) | (bB << 8) | b3;
      s_kth = kth;
      s_kth_scaled = key2f(kth) / temp;
    }
    __syncthreads();
    spec_ok = (s_kth >= SPEC_KEY + SLACK);
    if (spec_ok) {
      gumbel_argmax_cand(cand_key, cand_idx, cnt, s_kth_scaled, temp,
                         jbase, hist, out, r);
      return;
    }
    __syncthreads();
  }

  // full-histogram fallback
  for (int i = tid; i < NBIN; i += 1024) hist[i] = 0u;
  if (tid == 0) s_cnt = 0u;
  __syncthreads();
  for (int i = tid; i < n4; i += 1024) {
    float4 x = row4[i];
    atomicAdd(&hist[f2key(x.x) >> 20], 1u);
    atomicAdd(&hist[f2key(x.y) >> 20], 1u);
    atomicAdd(&hist[f2key(x.z) >> 20], 1u);
    atomicAdd(&hist[f2key(x.w) >> 20], 1u);
  }
  for (int i = (n4 << 2) + tid; i < V; i += 1024)
    atomicAdd(&hist[f2key(row[i]) >> 20], 1u);
  __syncthreads();
  find4096(hist, super, K, &s_bin, &s_rank);
  const uint32_t b1 = s_bin;
  const uint32_t r1 = s_rank;

  for (int i = tid; i < NBIN; i += 1024) hist[i] = 0u;
  __syncthreads();
  for (int i = tid; i < V; i += 1024) {
    uint32_t key = f2key(row[i]);
    if ((key >> 20) == b1) atomicAdd(&hist[(key >> 8) & 0xFFFu], 1u);
  }
  __syncthreads();
  find4096(hist, super, r1, &s_bin, &s_rank);
  const uint32_t b2 = s_bin; const uint32_t r2 = s_rank;
  for (int i = tid; i < 256; i += 1024) hist[i] = 0u;
  __syncthreads();
  for (int i = tid; i < V; i += 1024) {
    uint32_t key = f2key(row[i]);
    if ((key >> 8) == ((b1 << 12) | b2)) atomicAdd(&hist[key & 0xFFu], 1u);
  }
  __syncthreads();
  if (tid == 0) {
    uint32_t acc = 0; uint32_t b3 = 0;
    for (int i = 255; i >= 0; --i) {
      if (acc + hist[i] >= r2) { b3 = (uint32_t)i; break; }
      acc += hist[i];
    }
    uint32_t kth = (b1 << 20) | (b2 << 8) | b3;
    s_kth = kth;
    s_kth_scaled = key2f(kth) / temp;
  }
  __syncthreads();
  const float kth_scaled = s_kth_scaled;

  float bv = -INFINITY;
  int bi = 0x7FFFFFFF;
  for (int i = tid; i < V; i += 1024) {
    float x = row[i];
    float sc = x / temp;
    if (sc >= kth_scaled) {
      float g = gumbel_at(jbase + (uint32_t)i);
      float val = sc + g;
      if (val > bv || (val == bv && i < bi)) { bv = val; bi = i; }
    }
  }
#pragma unroll
  for (int d = 32; d > 0; d >>= 1) {
    float ov = __shfl_down(bv, d, 64);
    int oi = __shfl_down(bi, d, 64);
    if (ov > bv || (ov == bv && oi < bi)) { bv = ov; bi = oi; }
  }
  __syncthreads();
  {
    float* rv = (float*)hist;
    int*   ri = (int*)(hist + 64);
    int lane = tid & 63, wid = tid >> 6;
    if (lane == 0) { rv[wid] = bv; ri[wid] = bi; }
    __syncthreads();
    if (tid == 0) {
      float fv = rv[0]; int fi = ri[0];
      for (int w2 = 1; w2 < 16; ++w2) {
        float ov = rv[w2]; int oi = ri[w2];
        if (ov > fv || (ov == fv && oi < fi)) { fv = ov; fi = oi; }
      }
      out[r] = fi;
    }
  }
}

extern "C" void kernel_launch(void* const* d_in, const int* in_sizes, int n_in,
                              void* d_out, int out_size, void* d_ws, size_t ws_size,
                              hipStream_t stream) {
  const float* logits = (const float*)d_in[0];
  const float* temps  = (const float*)d_in[1];
  const int*   topk   = (const int*)d_in[2];
  int* out = (int*)d_out;
  const int B = in_sizes[1];           // 256
  const int V = in_sizes[0] / B;       // 128000

  // ws layout: [seg_cnts: B*SEG u32][done: B u32][entries: B*SEG*LCAP uint2]
  const size_t segcnt_bytes = (size_t)B * SEG * sizeof(uint32_t);
  const size_t done_bytes   = (size_t)B * sizeof(uint32_t);
  const size_t entry_bytes  = (size_t)B * SEG * LCAP * sizeof(uint2);

  if (ws_size >= segcnt_bytes + done_bytes + entry_bytes) {
    uint32_t* seg_cnts = (uint32_t*)d_ws;
    uint32_t* done     = (uint32_t*)((char*)d_ws + segcnt_bytes);
    uint2*    entries  = (uint2*)((char*)d_ws + segcnt_bytes + done_bytes);
    hipMemsetAsync(done, 0, done_bytes, stream);
    fused_kernel<<<B * SEG, CBLOCK, 0, stream>>>(logits, temps, topk, out, V,
                                                 seg_cnts, entries, done);
  } else {
    sampler_mono<<<B, 1024, 0, stream>>>(logits, temps, topk, out, B, V);
  }
}

// Round 8
// 36.945 us; speedup vs baseline: 8.1357x; 8.1357x over previous
//
#include <hip/hip_runtime.h>
#include <stdint.h>
#include <math.h>

// ---------------------------------------------------------------------------
// Sampler: temperature-scale -> top-k threshold -> Gumbel-max categorical.
// Exact reproduction of the JAX reference (threefry partitionable, key 42).
//
// R7 structure (two kernels, zero global atomics, zero fences; R6's fused
// version lost 12x to __threadfence L2 writebacks + LDS-capped occupancy):
//   collect  : B*SEG blocks x 256 thr, SEG=8 -> 2048 blocks = exactly
//              8 blocks/CU, whole grid co-resident in ONE scheduling round.
//              8-deep float4 loads, LDS-compact x >= SPEC_F, copy to private
//              slot, write per-segment count.
//   finalize : B blocks x 1024 thr. Gather <=2048 candidates, exact kth via
//              3-level histogram with wave-parallel select, exact division
//              filter, gumbel + shfl argmax. Fallbacks for speculation
//              failure (full-histogram re-read) and tiny ws (mono kernel).
// ---------------------------------------------------------------------------

#define BLOCK 1024
#define CBLOCK 256
#define SEG 8
#define LCAP 256             // per-segment slot; E[cnt]~99 for N(0,1) segments
#define NBIN  4096
#define TOTC  (SEG * LCAP)   // 2048
#define SLACK 64u
#define SPEC_F 2.5f
#define SPEC_KEY 0xC0200000u // f2key(2.5f)

__device__ __forceinline__ uint32_t rotl32(uint32_t x, uint32_t r) {
  return (x << r) | (x >> (32u - r));
}

__device__ __forceinline__ uint32_t f2key(float x) {
  uint32_t b = __float_as_uint(x);
  return (b & 0x80000000u) ? ~b : (b | 0x80000000u);
}
__device__ __forceinline__ float key2f(uint32_t k) {
  uint32_t b = (k & 0x80000000u) ? (k & 0x7FFFFFFFu) : ~k;
  return __uint_as_float(b);
}

// Threefry-2x32, key = (0, 42)
__device__ __forceinline__ void tf2x32(uint32_t x0, uint32_t x1,
                                       uint32_t &o0, uint32_t &o1) {
  const uint32_t k0 = 0u, k1 = 42u;
  const uint32_t k2 = k0 ^ k1 ^ 0x1BD11BDAu;
  x0 += k0; x1 += k1;
#define TF_R(r) { x0 += x1; x1 = rotl32(x1, (r)); x1 ^= x0; }
  TF_R(13u) TF_R(15u) TF_R(26u) TF_R(6u)
  x0 += k1; x1 += k2 + 1u;
  TF_R(17u) TF_R(29u) TF_R(16u) TF_R(24u)
  x0 += k2; x1 += k0 + 2u;
  TF_R(13u) TF_R(15u) TF_R(26u) TF_R(6u)
  x0 += k0; x1 += k1 + 3u;
  TF_R(17u) TF_R(29u) TF_R(16u) TF_R(24u)
  x0 += k1; x1 += k2 + 4u;
  TF_R(13u) TF_R(15u) TF_R(26u) TF_R(6u)
  x0 += k2; x1 += k0 + 5u;
#undef TF_R
  o0 = x0; o1 = x1;
}

__device__ __forceinline__ float gumbel_at(uint32_t j) {
  uint32_t o0, o1;
  tf2x32(0u, j, o0, o1);
  uint32_t bits = o0 ^ o1;
  float f = __uint_as_float((bits >> 9) | 0x3F800000u) - 1.0f;
  const float TINY = 1.17549435e-38f;
  float u = (f == 0.0f) ? TINY : f;
  return -logf(-logf(u));
}

// ---- wave-parallel descending-rank select over 64 bins -------------------
// tid<64 participate. Thread t supplies v = count of bin (63-t). Returns
// (wave-uniform) the bin holding the Kt-th largest and 1-based in-bin rank.
__device__ __forceinline__ void wave_sel64(uint32_t v, uint32_t Kt,
                                           uint32_t &sel, uint32_t &rank) {
  const int lane = threadIdx.x & 63;
  uint32_t P = v;
#pragma unroll
  for (int d = 1; d < 64; d <<= 1) {
    uint32_t n = __shfl_up(P, d, 64);
    if (lane >= d) P += n;
  }
  unsigned long long m = __ballot(P >= Kt);
  int t0 = (int)__ffsll(m) - 1;
  uint32_t Pt = __shfl(P, t0, 64);
  uint32_t vt = __shfl(v, t0, 64);
  sel = (uint32_t)(63 - t0);
  rank = Kt - (Pt - vt);
}

// ---- serial select over hist[4096] (fallback paths only) ------------------
__device__ void find4096(uint32_t* hist, uint32_t* super, uint32_t Kt,
                         uint32_t* s_bin, uint32_t* s_rank) {
  const int tid = threadIdx.x;
  if (tid < 64) {
    uint32_t s = 0;
    for (int i = 0; i < 64; ++i) s += hist[tid * 64 + i];
    super[tid] = s;
  }
  __syncthreads();
  if (tid == 0) {
    uint32_t acc = 0; int sb = 0;
    for (int s = 63; s >= 0; --s) {
      if (acc + super[s] >= Kt) { sb = s; break; }
      acc += super[s];
    }
    uint32_t bfound = (uint32_t)(sb * 64);
    for (int i = 63; i >= 0; --i) {
      uint32_t bin = (uint32_t)(sb * 64 + i);
      if (acc + hist[bin] >= Kt) { bfound = bin; break; }
      acc += hist[bin];
    }
    *s_bin = bfound; *s_rank = Kt - acc;
  }
  __syncthreads();
}

// exact kth-largest among cand[0:cnt] (serial select; fallback only)
__device__ void kth_of_cand(const uint32_t* cand_key, uint32_t cnt, uint32_t K,
                            uint32_t* hist, uint32_t* super,
                            uint32_t* s_bin, uint32_t* s_rank, uint32_t* s_kth) {
  const int tid = threadIdx.x;
  const int bs = blockDim.x;
  for (int i = tid; i < NBIN; i += bs) hist[i] = 0u;
  __syncthreads();
  for (int i = tid; i < (int)cnt; i += bs)
    atomicAdd(&hist[cand_key[i] >> 20], 1u);
  __syncthreads();
  find4096(hist, super, K, s_bin, s_rank);
  const uint32_t bA = *s_bin; const uint32_t rA = *s_rank;

  for (int i = tid; i < NBIN; i += bs) hist[i] = 0u;
  __syncthreads();
  for (int i = tid; i < (int)cnt; i += bs) {
    uint32_t key = cand_key[i];
    if ((key >> 20) == bA) atomicAdd(&hist[(key >> 8) & 0xFFFu], 1u);
  }
  __syncthreads();
  find4096(hist, super, rA, s_bin, s_rank);
  const uint32_t bB = *s_bin; const uint32_t rB = *s_rank;

  for (int i = tid; i < 256; i += bs) hist[i] = 0u;
  __syncthreads();
  for (int i = tid; i < (int)cnt; i += bs) {
    uint32_t key = cand_key[i];
    if ((key >> 8) == ((bA << 12) | bB)) atomicAdd(&hist[key & 0xFFu], 1u);
  }
  __syncthreads();
  if (tid == 0) {
    uint32_t acc = 0; uint32_t b3 = 0;
    for (int i = 255; i >= 0; --i) {
      if (acc + hist[i] >= rB) { b3 = (uint32_t)i; break; }
      acc += hist[i];
    }
    *s_kth = (bA << 20) | (bB << 8) | b3;
  }
  __syncthreads();
}

// gumbel-argmax over kept candidates; shfl wave-reduce + serial wave combine
__device__ void gumbel_argmax_cand(const uint32_t* cand_key, const int* cand_idx,
                                   uint32_t cnt, float kth_scaled, float temp,
                                   uint32_t jbase, uint32_t* scratch,
                                   int* out, int r) {
  const int tid = threadIdx.x;
  const int lane = tid & 63;
  const int wid = tid >> 6;
  float bv = -INFINITY;
  int bi = 0x7FFFFFFF;
  for (int i = tid; i < (int)cnt; i += blockDim.x) {
    float sc = key2f(cand_key[i]) / temp;
    if (sc >= kth_scaled) {
      int v = cand_idx[i];
      float g = gumbel_at(jbase + (uint32_t)v);
      float val = sc + g;
      if (val > bv || (val == bv && v < bi)) { bv = val; bi = v; }
    }
  }
#pragma unroll
  for (int d = 32; d > 0; d >>= 1) {
    float ov = __shfl_down(bv, d, 64);
    int oi = __shfl_down(bi, d, 64);
    if (ov > bv || (ov == bv && oi < bi)) { bv = ov; bi = oi; }
  }
  __syncthreads();
  float* rv = (float*)scratch;
  int*   ri = (int*)(scratch + 64);
  if (lane == 0) { rv[wid] = bv; ri[wid] = bi; }
  __syncthreads();
  if (tid == 0) {
    int nw = (int)(blockDim.x >> 6);
    float fv = rv[0]; int fi = ri[0];
    for (int w = 1; w < nw; ++w) {
      float ov = rv[w]; int oi = ri[w];
      if (ov > fv || (ov == fv && oi < fi)) { fv = ov; fi = oi; }
    }
    out[r] = fi;
  }
}

// ======================= kernel 1: collect =================================
__global__ __launch_bounds__(CBLOCK)
void collect_kernel(const float* __restrict__ logits, int V,
                    uint32_t* __restrict__ seg_cnts,
                    uint2* __restrict__ entries) {
  const int r   = blockIdx.x / SEG;
  const int seg = blockIdx.x % SEG;
  const int tid = threadIdx.x;
  const float* row = logits + (size_t)r * (size_t)V;
  const float4* row4 = (const float4*)row;
  const int n4 = V >> 2;
  const int chunk = (n4 + SEG - 1) / SEG;
  const int s4 = seg * chunk;
  const int e4 = min(n4, s4 + chunk);

  __shared__ uint32_t l_cnt;
  __shared__ uint32_t l_key[LCAP];
  __shared__ uint32_t l_idx[LCAP];
  if (tid == 0) l_cnt = 0u;
  __syncthreads();

  for (int i = s4 + tid; i < e4; i += 8 * CBLOCK) {
    float4 x[8];
#pragma unroll
    for (int k = 0; k < 8; ++k) {
      int idx = i + k * CBLOCK;
      x[k] = (idx < e4) ? row4[idx] : make_float4(0.f, 0.f, 0.f, 0.f);
    }
#pragma unroll
    for (int k = 0; k < 8; ++k) {
      int idx = i + k * CBLOCK;
      if (x[k].x >= SPEC_F) { uint32_t p = atomicAdd(&l_cnt, 1u);
        if (p < LCAP) { l_key[p] = f2key(x[k].x); l_idx[p] = ((uint32_t)idx << 2) + 0; } }
      if (x[k].y >= SPEC_F) { uint32_t p = atomicAdd(&l_cnt, 1u);
        if (p < LCAP) { l_key[p] = f2key(x[k].y); l_idx[p] = ((uint32_t)idx << 2) + 1; } }
      if (x[k].z >= SPEC_F) { uint32_t p = atomicAdd(&l_cnt, 1u);
        if (p < LCAP) { l_key[p] = f2key(x[k].z); l_idx[p] = ((uint32_t)idx << 2) + 2; } }
      if (x[k].w >= SPEC_F) { uint32_t p = atomicAdd(&l_cnt, 1u);
        if (p < LCAP) { l_key[p] = f2key(x[k].w); l_idx[p] = ((uint32_t)idx << 2) + 3; } }
    }
  }
  if (seg == SEG - 1) {
    for (int j = (n4 << 2) + tid; j < V; j += CBLOCK) {
      float x = row[j];
      if (x >= SPEC_F) {
        uint32_t p = atomicAdd(&l_cnt, 1u);
        if (p < LCAP) { l_key[p] = f2key(x); l_idx[p] = (uint32_t)j; }
      }
    }
  }
  __syncthreads();
  const uint32_t c = l_cnt;
  uint2* dst = entries + ((size_t)r * SEG + (size_t)seg) * LCAP;
  const uint32_t w = (c < LCAP) ? c : LCAP;
  for (uint32_t k = tid; k < w; k += CBLOCK)
    dst[k] = make_uint2(l_key[k], l_idx[k]);
  if (tid == 0) seg_cnts[r * SEG + seg] = c;   // true count (may exceed LCAP)
}

// ======================= kernel 2: finalize ================================
__global__ __launch_bounds__(BLOCK)
void finalize_kernel(const float* __restrict__ logits,
                     const float* __restrict__ temps,
                     const int* __restrict__ topk_p,
                     int* __restrict__ out, int V,
                     const uint32_t* __restrict__ seg_cnts,
                     const uint2* __restrict__ entries) {
  const int r = blockIdx.x;
  const int tid = threadIdx.x;
  const uint32_t K = (uint32_t)(*topk_p);
  const float temp = temps[r];
  const float* row = logits + (size_t)r * (size_t)V;
  const uint32_t jbase = (uint32_t)r * (uint32_t)V;

  __shared__ uint32_t hist[NBIN];
  __shared__ uint32_t super[64];
  __shared__ uint32_t cand_key[TOTC];
  __shared__ int      cand_idx[TOTC];
  __shared__ uint32_t scnt[SEG];
  __shared__ uint32_t soff[SEG + 1];
  __shared__ uint32_t s_ok;
  __shared__ uint32_t s_cnt, s_bin, s_rank, s_kth;
  __shared__ float    s_kth_scaled;

  if (tid < SEG) scnt[tid] = seg_cnts[r * SEG + tid];
  __syncthreads();
  if (tid == 0) {
    uint32_t acc = 0; uint32_t ok = 1;
    for (int s = 0; s < SEG; ++s) {
      soff[s] = acc;
      uint32_t c = scnt[s];
      if (c > LCAP) ok = 0;
      acc += (c < LCAP) ? c : LCAP;
    }
    soff[SEG] = acc;
    s_ok = ok;
  }
  __syncthreads();
  const uint32_t cnt = soff[SEG];

  if (s_ok && cnt >= K) {
    // ---- parallel gather over the fixed SEG x LCAP grid ----
    const uint2* base = entries + (size_t)r * TOTC;
    for (int idx = tid; idx < TOTC; idx += BLOCK) {
      int s = idx >> 8;              // / LCAP (=256)
      int k = idx & (LCAP - 1);
      if ((uint32_t)k < scnt[s]) {
        uint2 e = base[idx];
        uint32_t p = soff[s] + (uint32_t)k;
        cand_key[p] = e.x; cand_idx[p] = (int)e.y;
      }
    }
    __syncthreads();

    // ---- exact kth: 3-level histogram, wave-parallel select ----
    for (int i = tid; i < NBIN; i += BLOCK) hist[i] = 0u;
    __syncthreads();
    for (int i = tid; i < (int)cnt; i += BLOCK)
      atomicAdd(&hist[cand_key[i] >> 20], 1u);
    __syncthreads();
    if (tid < 64) {
      uint32_t s = 0;
      for (int i = 0; i < 64; ++i) s += hist[tid * 64 + i];
      super[tid] = s;
    }
    __syncthreads();
    if (tid < 64) {
      uint32_t sb, rs;
      wave_sel64(super[63 - tid], K, sb, rs);
      uint32_t s2, r2;
      wave_sel64(hist[sb * 64 + (63 - tid)], rs, s2, r2);
      if (tid == 0) { s_bin = sb * 64 + s2; s_rank = r2; }
    }
    __syncthreads();
    const uint32_t binA = s_bin;
    const uint32_t rA = s_rank;

    for (int i = tid; i < NBIN; i += BLOCK) hist[i] = 0u;
    __syncthreads();
    for (int i = tid; i < (int)cnt; i += BLOCK) {
      uint32_t key = cand_key[i];
      if ((key >> 20) == binA) atomicAdd(&hist[(key >> 8) & 0xFFFu], 1u);
    }
    __syncthreads();
    if (tid < 64) {
      uint32_t s = 0;
      for (int i = 0; i < 64; ++i) s += hist[tid * 64 + i];
      super[tid] = s;
    }
    __syncthreads();
    if (tid < 64) {
      uint32_t sb, rs;
      wave_sel64(super[63 - tid], rA, sb, rs);
      uint32_t s2, r2;
      wave_sel64(hist[sb * 64 + (63 - tid)], rs, s2, r2);
      if (tid == 0) { s_bin = sb * 64 + s2; s_rank = r2; }
    }
    __syncthreads();
    const uint32_t binB = s_bin;
    const uint32_t rB = s_rank;

    for (int i = tid; i < 256; i += BLOCK) hist[i] = 0u;
    __syncthreads();
    for (int i = tid; i < (int)cnt; i += BLOCK) {
      uint32_t key = cand_key[i];
      if ((key >> 8) == ((binA << 12) | binB)) atomicAdd(&hist[key & 0xFFu], 1u);
    }
    __syncthreads();
    if (tid < 64) {
      uint32_t mi = 63 - tid;
      uint32_t v = hist[mi * 4] + hist[mi * 4 + 1] + hist[mi * 4 + 2] + hist[mi * 4 + 3];
      uint32_t mm, rm;
      wave_sel64(v, rB, mm, rm);
      if (tid == 0) {
        uint32_t acc = 0; uint32_t b3 = mm * 4;
        for (int j = 3; j >= 0; --j) {
          uint32_t cc = hist[mm * 4 + j];
          if (acc + cc >= rm) { b3 = mm * 4 + (uint32_t)j; break; }
          acc += cc;
        }
        uint32_t kth = (binA << 20) | (binB << 8) | b3;
        s_kth = kth;
        s_kth_scaled = key2f(kth) / temp;
      }
    }
    __syncthreads();
    if (s_kth >= SPEC_KEY + SLACK) {
      gumbel_argmax_cand(cand_key, cand_idx, cnt, s_kth_scaled, temp,
                         jbase, hist, out, r);
      return;
    }
    __syncthreads();
  }

  // ---------------- fallback: full histogram over the row (L3-warm) -------
  const int n4 = V >> 2;
  const float4* row4 = (const float4*)row;
  for (int i = tid; i < NBIN; i += BLOCK) hist[i] = 0u;
  if (tid == 0) s_cnt = 0u;
  __syncthreads();
  for (int i = tid; i < n4; i += BLOCK) {
    float4 x = row4[i];
    atomicAdd(&hist[f2key(x.x) >> 20], 1u);
    atomicAdd(&hist[f2key(x.y) >> 20], 1u);
    atomicAdd(&hist[f2key(x.z) >> 20], 1u);
    atomicAdd(&hist[f2key(x.w) >> 20], 1u);
  }
  for (int i = (n4 << 2) + tid; i < V; i += BLOCK)
    atomicAdd(&hist[f2key(row[i]) >> 20], 1u);
  __syncthreads();
  find4096(hist, super, K, &s_bin, &s_rank);
  const uint32_t b1 = s_bin;
  const uint32_t r1 = s_rank;

  uint32_t lo = b1 << 20;
  lo = (lo >= SLACK) ? (lo - SLACK) : 0u;
  if (tid == 0) s_cnt = 0u;
  __syncthreads();
  for (int i = tid; i < V; i += BLOCK) {
    uint32_t key = f2key(row[i]);
    if (key >= lo) {
      uint32_t p = atomicAdd(&s_cnt, 1u);
      if (p < TOTC) { cand_key[p] = key; cand_idx[p] = i; }
    }
  }
  __syncthreads();
  const uint32_t cnt2 = s_cnt;

  if (cnt2 <= TOTC) {
    kth_of_cand(cand_key, cnt2, K, hist, super, &s_bin, &s_rank, &s_kth);
    if (tid == 0) s_kth_scaled = key2f(s_kth) / temp;
    __syncthreads();
    gumbel_argmax_cand(cand_key, cand_idx, cnt2, s_kth_scaled, temp,
                       jbase, hist, out, r);
    return;
  }

  // pathological duplicate-heavy rows: refine + argmax from global memory
  for (int i = tid; i < NBIN; i += BLOCK) hist[i] = 0u;
  __syncthreads();
  for (int i = tid; i < V; i += BLOCK) {
    uint32_t key = f2key(row[i]);
    if ((key >> 20) == b1) atomicAdd(&hist[(key >> 8) & 0xFFFu], 1u);
  }
  __syncthreads();
  find4096(hist, super, r1, &s_bin, &s_rank);
  const uint32_t b2 = s_bin; const uint32_t r2 = s_rank;
  for (int i = tid; i < 256; i += BLOCK) hist[i] = 0u;
  __syncthreads();
  for (int i = tid; i < V; i += BLOCK) {
    uint32_t key = f2key(row[i]);
    if ((key >> 8) == ((b1 << 12) | b2)) atomicAdd(&hist[key & 0xFFu], 1u);
  }
  __syncthreads();
  if (tid == 0) {
    uint32_t acc = 0; uint32_t b3 = 0;
    for (int i = 255; i >= 0; --i) {
      if (acc + hist[i] >= r2) { b3 = (uint32_t)i; break; }
      acc += hist[i];
    }
    uint32_t kth = (b1 << 20) | (b2 << 8) | b3;
    s_kth = kth;
    s_kth_scaled = key2f(kth) / temp;
  }
  __syncthreads();
  const float kth_scaled = s_kth_scaled;

  float bv = -INFINITY;
  int bi = 0x7FFFFFFF;
  for (int i = tid; i < V; i += BLOCK) {
    float x = row[i];
    float sc = x / temp;
    if (sc >= kth_scaled) {
      float g = gumbel_at(jbase + (uint32_t)i);
      float val = sc + g;
      if (val > bv || (val == bv && i < bi)) { bv = val; bi = i; }
    }
  }
#pragma unroll
  for (int d = 32; d > 0; d >>= 1) {
    float ov = __shfl_down(bv, d, 64);
    int oi = __shfl_down(bi, d, 64);
    if (ov > bv || (ov == bv && oi < bi)) { bv = ov; bi = oi; }
  }
  __syncthreads();
  {
    float* rv = (float*)hist;
    int*   ri = (int*)(hist + 64);
    int lane = tid & 63, wid = tid >> 6;
    if (lane == 0) { rv[wid] = bv; ri[wid] = bi; }
    __syncthreads();
    if (tid == 0) {
      int nw = BLOCK >> 6;
      float fv = rv[0]; int fi = ri[0];
      for (int w2 = 1; w2 < nw; ++w2) {
        float ov = rv[w2]; int oi = ri[w2];
        if (ov > fv || (ov == fv && oi < fi)) { fv = ov; fi = oi; }
      }
      out[r] = fi;
    }
  }
}

// ============== monolithic kernel (used only if ws too small) ==============
__global__ __launch_bounds__(BLOCK)
void sampler_mono(const float* __restrict__ logits,
                  const float* __restrict__ temps,
                  const int* __restrict__ topk_p,
                  int* __restrict__ out, int B, int V) {
  const int r = blockIdx.x;
  const int tid = threadIdx.x;
  const uint32_t K = (uint32_t)(*topk_p);
  const float temp = temps[r];
  const float* row = logits + (size_t)r * (size_t)V;
  const uint32_t jbase = (uint32_t)r * (uint32_t)V;

  __shared__ uint32_t hist[NBIN];
  __shared__ uint32_t super[64];
  __shared__ uint32_t cand_key[TOTC];
  __shared__ int      cand_idx[TOTC];
  __shared__ uint32_t s_cnt, s_bin, s_rank, s_kth;
  __shared__ float    s_kth_scaled;

  const int n4 = V >> 2;
  const float4* row4 = (const float4*)row;

  if (tid == 0) s_cnt = 0u;
  __syncthreads();
  for (int i = tid; i < n4; i += BLOCK) {
    float4 x = row4[i];
    float s[4] = {x.x, x.y, x.z, x.w};
#pragma unroll
    for (int q = 0; q < 4; ++q) {
      if (s[q] >= SPEC_F) {
        uint32_t p = atomicAdd(&s_cnt, 1u);
        if (p < TOTC) { cand_key[p] = f2key(s[q]); cand_idx[p] = (i << 2) + q; }
      }
    }
  }
  for (int i = (n4 << 2) + tid; i < V; i += BLOCK) {
    float x = row[i];
    if (x >= SPEC_F) {
      uint32_t p = atomicAdd(&s_cnt, 1u);
      if (p < TOTC) { cand_key[p] = f2key(x); cand_idx[p] = i; }
    }
  }
  __syncthreads();
  uint32_t cnt = s_cnt;
  if (cnt >= K && cnt <= TOTC) {
    kth_of_cand(cand_key, cnt, K, hist, super, &s_bin, &s_rank, &s_kth);
    if (s_kth >= SPEC_KEY + SLACK) {
      if (tid == 0) s_kth_scaled = key2f(s_kth) / temp;
      __syncthreads();
      gumbel_argmax_cand(cand_key, cand_idx, cnt, s_kth_scaled, temp,
                         jbase, hist, out, r);
      return;
    }
    __syncthreads();
  }

  // full-histogram fallback
  for (int i = tid; i < NBIN; i += BLOCK) hist[i] = 0u;
  if (tid == 0) s_cnt = 0u;
  __syncthreads();
  for (int i = tid; i < n4; i += BLOCK) {
    float4 x = row4[i];
    atomicAdd(&hist[f2key(x.x) >> 20], 1u);
    atomicAdd(&hist[f2key(x.y) >> 20], 1u);
    atomicAdd(&hist[f2key(x.z) >> 20], 1u);
    atomicAdd(&hist[f2key(x.w) >> 20], 1u);
  }
  for (int i = (n4 << 2) + tid; i < V; i += BLOCK)
    atomicAdd(&hist[f2key(row[i]) >> 20], 1u);
  __syncthreads();
  find4096(hist, super, K, &s_bin, &s_rank);
  const uint32_t b1 = s_bin;
  const uint32_t r1 = s_rank;

  uint32_t lo = b1 << 20;
  lo = (lo >= SLACK) ? (lo - SLACK) : 0u;
  if (tid == 0) s_cnt = 0u;
  __syncthreads();
  for (int i = tid; i < V; i += BLOCK) {
    uint32_t key = f2key(row[i]);
    if (key >= lo) {
      uint32_t p = atomicAdd(&s_cnt, 1u);
      if (p < TOTC) { cand_key[p] = key; cand_idx[p] = i; }
    }
  }
  __syncthreads();
  const uint32_t cnt2 = s_cnt;

  if (cnt2 <= TOTC) {
    kth_of_cand(cand_key, cnt2, K, hist, super, &s_bin, &s_rank, &s_kth);
    if (tid == 0) s_kth_scaled = key2f(s_kth) / temp;
    __syncthreads();
    gumbel_argmax_cand(cand_key, cand_idx, cnt2, s_kth_scaled, temp,
                       jbase, hist, out, r);
    return;
  }

  for (int i = tid; i < NBIN; i += BLOCK) hist[i] = 0u;
  __syncthreads();
  for (int i = tid; i < V; i += BLOCK) {
    uint32_t key = f2key(row[i]);
    if ((key >> 20) == b1) atomicAdd(&hist[(key >> 8) & 0xFFFu], 1u);
  }
  __syncthreads();
  find4096(hist, super, r1, &s_bin, &s_rank);
  const uint32_t b2 = s_bin; const uint32_t r2 = s_rank;
  for (int i = tid; i < 256; i += BLOCK) hist[i] = 0u;
  __syncthreads();
  for (int i = tid; i < V; i += BLOCK) {
    uint32_t key = f2key(row[i]);
    if ((key >> 8) == ((b1 << 12) | b2)) atomicAdd(&hist[key & 0xFFu], 1u);
  }
  __syncthreads();
  if (tid == 0) {
    uint32_t acc = 0; uint32_t b3 = 0;
    for (int i = 255; i >= 0; --i) {
      if (acc + hist[i] >= r2) { b3 = (uint32_t)i; break; }
      acc += hist[i];
    }
    uint32_t kth = (b1 << 20) | (b2 << 8) | b3;
    s_kth = kth;
    s_kth_scaled = key2f(kth) / temp;
  }
  __syncthreads();
  const float kth_scaled = s_kth_scaled;

  float bv = -INFINITY;
  int bi = 0x7FFFFFFF;
  for (int i = tid; i < V; i += BLOCK) {
    float x = row[i];
    float sc = x / temp;
    if (sc >= kth_scaled) {
      float g = gumbel_at(jbase + (uint32_t)i);
      float val = sc + g;
      if (val > bv || (val == bv && i < bi)) { bv = val; bi = i; }
    }
  }
#pragma unroll
  for (int d = 32; d > 0; d >>= 1) {
    float ov = __shfl_down(bv, d, 64);
    int oi = __shfl_down(bi, d, 64);
    if (ov > bv || (ov == bv && oi < bi)) { bv = ov; bi = oi; }
  }
  __syncthreads();
  {
    float* rv = (float*)hist;
    int*   ri = (int*)(hist + 64);
    int lane = tid & 63, wid = tid >> 6;
    if (lane == 0) { rv[wid] = bv; ri[wid] = bi; }
    __syncthreads();
    if (tid == 0) {
      float fv = rv[0]; int fi = ri[0];
      for (int w2 = 1; w2 < (BLOCK >> 6); ++w2) {
        float ov = rv[w2]; int oi = ri[w2];
        if (ov > fv || (ov == fv && oi < fi)) { fv = ov; fi = oi; }
      }
      out[r] = fi;
    }
  }
}

extern "C" void kernel_launch(void* const* d_in, const int* in_sizes, int n_in,
                              void* d_out, int out_size, void* d_ws, size_t ws_size,
                              hipStream_t stream) {
  const float* logits = (const float*)d_in[0];
  const float* temps  = (const float*)d_in[1];
  const int*   topk   = (const int*)d_in[2];
  int* out = (int*)d_out;
  const int B = in_sizes[1];           // 256
  const int V = in_sizes[0] / B;       // 128000

  // ws layout: [seg_cnts: B*SEG u32][entries: B*SEG*LCAP uint2]
  const size_t segcnt_bytes = (size_t)B * SEG * sizeof(uint32_t);
  const size_t entry_bytes  = (size_t)B * SEG * LCAP * sizeof(uint2);

  if (ws_size >= segcnt_bytes + entry_bytes) {
    uint32_t* seg_cnts = (uint32_t*)d_ws;
    uint2*    entries  = (uint2*)((char*)d_ws + segcnt_bytes);
    collect_kernel<<<B * SEG, CBLOCK, 0, stream>>>(logits, V, seg_cnts, entries);
    finalize_kernel<<<B, BLOCK, 0, stream>>>(logits, temps, topk, out, V,
                                             seg_cnts, entries);
  } else {
    sampler_mono<<<B, BLOCK, 0, stream>>>(logits, temps, topk, out, B, V);
  }
}